// Round 16
// baseline (511.582 us; speedup 1.0000x reference)
//
#include <hip/hip_runtime.h>
#include <math.h>

#define NB 8
#define SL 1024
#define DI 512
#define HH 8
#define KDN 64
#define VDN 64
#define ODN 512
#define ATT_SCALE 0.125f

// workspace layout (float units)
// [0,2M)  : KHI bf16 [H*N][S][KD] (8 MB)   (dead after attn)
// KLO_OFF : KLO bf16 (8 MB)                -> after attn: Wout' split planes (1 MB)
// V_OFF   : V bf16 [H*N][S][VD] (8 MB) + VT bf16 [H*N][VD][S] (8 MB)
// G_OFF   : (a) Wk/Wv transposed split-bf16 planes (2 MB, consumed by kvproj)
//           (b) g bf16 [S][S] (2 MB, from gsoftmax on)
// Y_OFF   : y f32 [N][S][H*VD] (16 MB)
#define KLO_OFF 2097152u
#define V_OFF   4194304u
#define G_OFF   8388608u
#define Y_OFF   9437184u

#define ORD_NEG_INF 0x007FFFFFu

typedef __attribute__((ext_vector_type(8))) short bf16x8;
typedef __attribute__((ext_vector_type(4))) float f32x4;

__device__ __forceinline__ unsigned fordu(float f) {
  unsigned b = __float_as_uint(f);
  return b ^ ((b & 0x80000000u) ? 0xFFFFFFFFu : 0x80000000u);
}
__device__ __forceinline__ float ifordu(unsigned k) {
  unsigned b = k ^ ((k & 0x80000000u) ? 0x80000000u : 0xFFFFFFFFu);
  return __uint_as_float(b);
}
__device__ __forceinline__ unsigned short f2bf(float f) {  // RNE f32->bf16
  unsigned u = __float_as_uint(f);
  unsigned r = (u + 0x7FFFu + ((u >> 16) & 1u)) >> 16;
  return (unsigned short)r;
}
__device__ __forceinline__ float bf2f(unsigned short h) {
  return __uint_as_float(((unsigned)h) << 16);
}

// --------------------- Wk/Wv -> transposed split-bf16 planes (in G region) ---
// wkthi/wktlo: [H*KD][DI]; wvthi/wvtlo: [H*VD][DI]. Consumed by kvproj; the
// G region is overwritten by gsoftmax afterwards. (r9-verified)
__global__ __launch_bounds__(256) void wprep_kernel(
    const float* __restrict__ Wk, const float* __restrict__ Wv, float* __restrict__ ws)
{
  __shared__ float tile[64][65];
  unsigned short* gbase = (unsigned short*)(ws + G_OFF);
  const int t = threadIdx.x;
  const int d0 = blockIdx.x * 64;
  const int hs = blockIdx.y;             // [0,16): h = hs&7, which = hs>>3
  const int h = hs & 7, which = hs >> 3;
  const float* W = (which == 0) ? (Wk + (size_t)h * DI * KDN) : (Wv + (size_t)h * DI * VDN);
  unsigned short* whi = gbase + (size_t)which * 524288 + (size_t)h * KDN * DI;
  unsigned short* wlo = whi + 262144;
  const int r = t >> 2, c4 = (t & 3) * 16;
#pragma unroll
  for (int j = 0; j < 4; ++j)
    *(float4*)&tile[r][c4 + j * 4] = *(const float4*)&W[(size_t)(d0 + r) * KDN + c4 + j * 4];
  __syncthreads();
  union { unsigned short u[16]; uint4 v[2]; } hi, lo;
#pragma unroll
  for (int j = 0; j < 16; ++j) {
    const float f = tile[c4 + j][r];
    const unsigned short h16 = f2bf(f);
    hi.u[j] = h16;
    lo.u[j] = f2bf(f - bf2f(h16));
  }
  const size_t o = (size_t)r * DI + d0 + c4;
  *(uint4*)&whi[o] = hi.v[0];
  *(uint4*)&whi[o + 8] = hi.v[1];
  *(uint4*)&wlo[o] = lo.v[0];
  *(uint4*)&wlo[o + 8] = lo.v[1];
}

// ------------------- kv proj: LDS-staged split-bf16 MFMA GEMM ---------------
// block: 256 thr / 4 waves; tile 64 rows x (64 kd + 64 vd), K=512 in BK=64.
// x staged per K-step as split-bf16 in LDS (row stride 72 ushorts = 144 B:
// 16B-aligned b128 fragments, 2-way bank alias only). B-fragments from the
// L2-resident wprep planes. 3-term split product (hh+hl+lh).
__global__ __launch_bounds__(256, 4) void kvproj_kernel(
    const float* __restrict__ x, const float* __restrict__ bk,
    const float* __restrict__ bv, float* __restrict__ ws)
{
  __shared__ unsigned short xsplit[2][64][72];   // 18,432 B; reused as f32 vtile[64][72]
  const unsigned short* gbase = (const unsigned short*)(ws + G_OFF);
  const unsigned short* wkthi = gbase;
  const unsigned short* wktlo = gbase + 262144;
  const unsigned short* wvthi = gbase + 524288;
  const unsigned short* wvtlo = gbase + 786432;
  unsigned short* khi = (unsigned short*)ws;
  unsigned short* klo = (unsigned short*)(ws + KLO_OFF);

  const int tid = threadIdx.x;
  const int lane = tid & 63;
  const int wave = tid >> 6;
  const int col = lane & 15, grp = lane >> 4;
  const int m0 = blockIdx.x * 64;
  const int h = blockIdx.y;
  const int n = m0 >> 10, s0 = m0 & 1023;

  f32x4 ack[4], acv[4];
#pragma unroll
  for (int odt = 0; odt < 4; ++odt) { ack[odt] = (f32x4){0,0,0,0}; acv[odt] = (f32x4){0,0,0,0}; }

  const int sr = tid >> 2;          // staging row 0..63
  const int sc = (tid & 3) * 16;    // staging col chunk

  for (int dt = 0; dt < 8; ++dt) {
    __syncthreads();
    // ---- stage x[m0..+64][dt*64..+64] as split bf16 ----
    {
      const float* xrow = &x[(size_t)(m0 + sr) * DI + dt * 64 + sc];
      union { unsigned short u[16]; uint4 v[2]; } hi, lo;
#pragma unroll
      for (int j4 = 0; j4 < 4; ++j4) {
        const float4 xv = *(const float4*)&xrow[j4 * 4];
        const float xf[4] = {xv.x, xv.y, xv.z, xv.w};
#pragma unroll
        for (int j = 0; j < 4; ++j) {
          const unsigned short h16 = f2bf(xf[j]);
          hi.u[j4 * 4 + j] = h16;
          lo.u[j4 * 4 + j] = f2bf(xf[j] - bf2f(h16));
        }
      }
      *(uint4*)&xsplit[0][sr][sc]     = hi.v[0];
      *(uint4*)&xsplit[0][sr][sc + 8] = hi.v[1];
      *(uint4*)&xsplit[1][sr][sc]     = lo.v[0];
      *(uint4*)&xsplit[1][sr][sc + 8] = lo.v[1];
    }
    __syncthreads();
    // ---- MFMA: 2 K-halves x 4 output tiles x (K + V) ----
#pragma unroll
    for (int half = 0; half < 2; ++half) {
      const bf16x8 ah = *(const bf16x8*)&xsplit[0][wave * 16 + col][half * 32 + grp * 8];
      const bf16x8 al = *(const bf16x8*)&xsplit[1][wave * 16 + col][half * 32 + grp * 8];
#pragma unroll
      for (int odt = 0; odt < 4; ++odt) {
        const size_t bo = (size_t)(h * 64 + odt * 16 + col) * DI + dt * 64 + half * 32 + grp * 8;
        const bf16x8 kh = *(const bf16x8*)&wkthi[bo];
        const bf16x8 kl = *(const bf16x8*)&wktlo[bo];
        ack[odt] = __builtin_amdgcn_mfma_f32_16x16x32_bf16(ah, kh, ack[odt], 0, 0, 0);
        ack[odt] = __builtin_amdgcn_mfma_f32_16x16x32_bf16(ah, kl, ack[odt], 0, 0, 0);
        ack[odt] = __builtin_amdgcn_mfma_f32_16x16x32_bf16(al, kh, ack[odt], 0, 0, 0);
        const bf16x8 vh = *(const bf16x8*)&wvthi[bo];
        const bf16x8 vl = *(const bf16x8*)&wvtlo[bo];
        acv[odt] = __builtin_amdgcn_mfma_f32_16x16x32_bf16(ah, vh, acv[odt], 0, 0, 0);
        acv[odt] = __builtin_amdgcn_mfma_f32_16x16x32_bf16(ah, vl, acv[odt], 0, 0, 0);
        acv[odt] = __builtin_amdgcn_mfma_f32_16x16x32_bf16(al, vh, acv[odt], 0, 0, 0);
      }
    }
  }

  // ---- epilogue: K split-stores (scalar, r9 pattern) + V via LDS round-trip
  const size_t hnbase = (size_t)(h * NB + n) * SL;
  __syncthreads();
  float* vtile = (float*)xsplit;    // [64][72] f32 view (18,432 B)
#pragma unroll
  for (int odt = 0; odt < 4; ++odt) {
    const int kd = odt * 16 + col;
    const float bkv = bk[h * KDN + kd];
    const float bvv = bv[h * VDN + kd];
#pragma unroll
    for (int r = 0; r < 4; ++r) {
      const int sl = wave * 16 + grp * 4 + r;
      const int s = s0 + sl;
      const float kf = ack[odt][r] + bkv;
      const unsigned short h16 = f2bf(kf);
      khi[(hnbase + s) * KDN + kd] = h16;
      klo[(hnbase + s) * KDN + kd] = f2bf(kf - bf2f(h16));
      vtile[sl * 72 + kd] = acv[odt][r] + bvv;
    }
  }
  __syncthreads();
  // V bf16 [s][vd] (coalesced) + VT bf16 [vd][s] (transpose) from vtile
  {
    unsigned short* vbf = (unsigned short*)(ws + V_OFF);
    unsigned short* vtb = vbf + 4194304u;
    union { unsigned short u[16]; uint4 v[2]; } pv, pt;
#pragma unroll
    for (int j = 0; j < 16; ++j) {
      pv.u[j] = f2bf(vtile[sr * 72 + sc + j]);      // row sr of V
      pt.u[j] = f2bf(vtile[(sc + j) * 72 + sr]);    // column sr (vd) of V
    }
    unsigned short* vrow = &vbf[(hnbase + s0 + sr) * VDN];
    *(uint4*)&vrow[sc] = pv.v[0];
    *(uint4*)&vrow[sc + 8] = pv.v[1];
    unsigned short* vt = vtb + hnbase * VDN;        // == hn * VDN * SL
    const size_t o = (size_t)sr * SL + s0 + sc;
    *(uint4*)&vt[o] = pt.v[0];
    *(uint4*)&vt[o + 8] = pt.v[1];
  }
}

// ------------------------------- graph softmax -> bf16 plane (G region) ----
__global__ __launch_bounds__(256) void gsoftmax_kernel(const float* __restrict__ gin, float* __restrict__ ws)
{
  unsigned short* ghi = (unsigned short*)(ws + G_OFF);
  const int row = blockIdx.x;
  const int tid = threadIdx.x;
  const int lane = tid & 63, wave = tid >> 6;
  __shared__ float red[4];
  __shared__ float red2[4];
  float v[4];
  float m = -INFINITY;
#pragma unroll
  for (int i = 0; i < 4; ++i) {
    v[i] = gin[(size_t)row * SL + tid + i * 256];
    m = fmaxf(m, v[i]);
  }
#pragma unroll
  for (int off = 32; off; off >>= 1) m = fmaxf(m, __shfl_xor(m, off));
  if (lane == 0) red[wave] = m;
  __syncthreads();
  m = fmaxf(fmaxf(red[0], red[1]), fmaxf(red[2], red[3]));
  float e[4];
  float s = 0.f;
#pragma unroll
  for (int i = 0; i < 4; ++i) { e[i] = __expf(v[i] - m); s += e[i]; }
#pragma unroll
  for (int off = 32; off; off >>= 1) s += __shfl_xor(s, off);
  if (lane == 0) red2[wave] = s;
  __syncthreads();
  s = red2[0] + red2[1] + red2[2] + red2[3];
  const float inv = 1.0f / s;
#pragma unroll
  for (int i = 0; i < 4; ++i) ghi[(size_t)row * SL + tid + i * 256] = f2bf(e[i] * inv);
}

// -------------------------------------------------------------- attention ---
// Frozen r12/r15 structure: 512 thr / 8 waves / 2 rows per wave, bounds (512,8)
// (measured-best; mild spill accepted), bf16-V PV gathers.
__global__ __launch_bounds__(512, 8) void attn_kernel(float* __restrict__ ws, const int* __restrict__ knn_p)
{
  __shared__ float S[16][260];    // 16.6 KB; reused as per-wave lists after capture
  const int tid = threadIdx.x;
  const int lane = tid & 63;
  const int wave = tid >> 6;      // 0..7
  const int q0 = blockIdx.x * 16;
  const int hn = blockIdx.y;
  const int h = hn >> 3, n = hn & 7;
  const int K = knn_p[0];
  const unsigned short* khi = (const unsigned short*)ws + (size_t)hn * SL * KDN;
  const unsigned short* klo = (const unsigned short*)(ws + KLO_OFF) + (size_t)hn * SL * KDN;
  const unsigned short* vb = (const unsigned short*)(ws + V_OFF) + (size_t)hn * (SL * VDN);
  float* y = ws + Y_OFF;

  const int col = lane & 15, grp = lane >> 4;
  const bf16x8 a0h = *(const bf16x8*)&khi[(size_t)(q0 + col) * KDN + grp * 8];
  const bf16x8 a1h = *(const bf16x8*)&khi[(size_t)(q0 + col) * KDN + 32 + grp * 8];
  const bf16x8 a0l = *(const bf16x8*)&klo[(size_t)(q0 + col) * KDN + grp * 8];
  const bf16x8 a1l = *(const bf16x8*)&klo[(size_t)(q0 + col) * KDN + 32 + grp * 8];

  const int T = q0 / 16 + 1;      // causal t-tiles needed
  const int rbase = wave * 2;

  float ev[2][8][2];              // per-row KEYS (never overwritten), static-indexed
#pragma unroll
  for (int rr = 0; rr < 2; ++rr)
#pragma unroll
    for (int c = 0; c < 8; ++c) {
      ev[rr][c][0] = __uint_as_float(ORD_NEG_INF);
      ev[rr][c][1] = __uint_as_float(ORD_NEG_INF);
    }

#pragma unroll
  for (int ph = 0; ph < 4; ++ph) {
    const int tlo = ph * 16;
    const int thi = (T < tlo + 16) ? T : (tlo + 16);
    if (thi > tlo) {            // block-uniform
      __syncthreads();
      for (int ti = tlo + wave; ti < thi; ti += 8) {
        const int t0 = ti * 16;
        const size_t bo = (size_t)(t0 + col) * KDN + grp * 8;
        const bf16x8 b0h = *(const bf16x8*)&khi[bo];
        const bf16x8 b1h = *(const bf16x8*)&khi[bo + 32];
        const bf16x8 b0l = *(const bf16x8*)&klo[bo];
        const bf16x8 b1l = *(const bf16x8*)&klo[bo + 32];
        f32x4 d = {0.f, 0.f, 0.f, 0.f};
        d = __builtin_amdgcn_mfma_f32_16x16x32_bf16(a0h, b0h, d, 0, 0, 0);
        d = __builtin_amdgcn_mfma_f32_16x16x32_bf16(a1h, b1h, d, 0, 0, 0);
        d = __builtin_amdgcn_mfma_f32_16x16x32_bf16(a0h, b0l, d, 0, 0, 0);
        d = __builtin_amdgcn_mfma_f32_16x16x32_bf16(a1h, b1l, d, 0, 0, 0);
        d = __builtin_amdgcn_mfma_f32_16x16x32_bf16(a0l, b0h, d, 0, 0, 0);
        d = __builtin_amdgcn_mfma_f32_16x16x32_bf16(a1l, b1h, d, 0, 0, 0);
        d = __builtin_amdgcn_mfma_f32_16x16x32_bf16(a0l, b0l, d, 0, 0, 0);
        d = __builtin_amdgcn_mfma_f32_16x16x32_bf16(a1l, b1l, d, 0, 0, 0);
        const int tl = t0 - ph * 256 + col;
#pragma unroll
        for (int r = 0; r < 4; ++r) S[grp * 4 + r][tl] = d[r];
      }
      __syncthreads();
#pragma unroll
      for (int rr = 0; rr < 2; ++rr) {
        const int q = q0 + rbase + rr;
        const int cmr = q >> 7;
#pragma unroll
        for (int cc = 0; cc < 2; ++cc) {
          const int c = ph * 2 + cc;
          if (c <= cmr) {
            const float2 sv = *(const float2*)&S[rbase + rr][cc * 128 + lane * 2];
            const int t0 = c * 128 + lane * 2;
            const unsigned k0 = (t0     <= q) ? fordu(sv.x * ATT_SCALE) : ORD_NEG_INF;
            const unsigned k1 = (t0 + 1 <= q) ? fordu(sv.y * ATT_SCALE) : ORD_NEG_INF;
            ev[rr][c][0] = __uint_as_float(k0);
            ev[rr][c][1] = __uint_as_float(k1);
          }
        }
      }
    }
  }
  __syncthreads();  // all rows captured -> reuse S as per-wave scratch

  float* elist = (float*)((char*)&S[0][0] + wave * 768);   // 128 f32 (8 waves x 768B = 6 KB)
  unsigned short* tlist = (unsigned short*)(elist + 128);  // 128 u16

#pragma unroll
  for (int rr = 0; rr < 2; ++rr) {
    const int q = q0 + rbase + rr;

    // ---- lane-max, wave max (mk), wave min-of-lane-maxes (t0k) on key bits ----
    unsigned lmax = __float_as_uint(ev[rr][0][0]);
#pragma unroll
    for (int c = 0; c < 8; ++c) {
      const unsigned a = __float_as_uint(ev[rr][c][0]);
      const unsigned b = __float_as_uint(ev[rr][c][1]);
      lmax = lmax > a ? lmax : a;
      lmax = lmax > b ? lmax : b;
    }
    unsigned mk = lmax, t0k = lmax;
#pragma unroll
    for (int off = 32; off; off >>= 1) {
      const unsigned om = (unsigned)__shfl_xor((int)mk, off);
      const unsigned ot = (unsigned)__shfl_xor((int)t0k, off);
      mk = mk > om ? mk : om;
      t0k = t0k < ot ? t0k : ot;
    }
    const float m = ifordu(mk);

    // ---- exact Kth-largest key: binary search on rank ----
    unsigned kth;
    if (q < K) {
      kth = ORD_NEG_INF;
    } else {
      unsigned lo = (K <= 64) ? t0k : 0u;
      unsigned hi = mk;
      while (lo < hi) {
        const unsigned mid = lo + ((hi - lo + 1) >> 1);
        int cnt = 0;
#pragma unroll
        for (int c = 0; c < 8; ++c) {
          cnt += (int)__popcll(__ballot(__float_as_uint(ev[rr][c][0]) >= mid));
          cnt += (int)__popcll(__ballot(__float_as_uint(ev[rr][c][1]) >= mid));
        }
        if (cnt >= K) lo = mid; else hi = mid - 1;
      }
      kth = lo;
    }

    // ---- compact kept KEYS into per-wave LDS lists (cap 128) ----
    const unsigned long long lt = (1ull << lane) - 1ull;
    int cnt = 0;
#pragma unroll
    for (int c = 0; c < 8; ++c) {
#pragma unroll
      for (int j = 0; j < 2; ++j) {
        const unsigned k = __float_as_uint(ev[rr][c][j]);
        const bool keep = (k >= kth) && (k != ORD_NEG_INF);
        const unsigned long long msk = __ballot(keep);
        if (keep) {
          const int pos = cnt + (int)__popcll(msk & lt);
          if (pos < 128) {
            elist[pos] = ev[rr][c][j];   // store KEY bits
            tlist[pos] = (unsigned short)(c * 128 + lane * 2 + j);
          }
        }
        cnt += (int)__popcll(msk);
      }
    }
    cnt = (cnt < 128) ? cnt : 128;

    // ---- exp only compacted entries (<=2/lane); Z via wave reduce ----
    float zp = 0.f;
    if (lane < cnt) {
      const float e = __expf(ifordu(__float_as_uint(elist[lane])) - m);
      elist[lane] = e;
      zp += e;
    }
    if (lane + 64 < cnt) {
      const float e = __expf(ifordu(__float_as_uint(elist[lane + 64])) - m);
      elist[lane + 64] = e;
      zp += e;
    }
    float Z = zp;
#pragma unroll
    for (int off = 32; off; off >>= 1) Z += __shfl_xor(Z, off);

    // ---- sparse PV: lane = vd (V gathered as bf16) ----
    float yacc = 0.f;
    int i2 = 0;
    for (; i2 + 4 <= cnt; i2 += 4) {
      const float4 e4 = *(const float4*)&elist[i2];
      const ushort4 t4 = *(const ushort4*)&tlist[i2];
      const float v0 = bf2f(vb[(size_t)t4.x * VDN + lane]);
      const float v1 = bf2f(vb[(size_t)t4.y * VDN + lane]);
      const float v2 = bf2f(vb[(size_t)t4.z * VDN + lane]);
      const float v3 = bf2f(vb[(size_t)t4.w * VDN + lane]);
      yacc = __fmaf_rn(e4.x, v0, yacc);
      yacc = __fmaf_rn(e4.y, v1, yacc);
      yacc = __fmaf_rn(e4.z, v2, yacc);
      yacc = __fmaf_rn(e4.w, v3, yacc);
    }
    for (; i2 < cnt; ++i2) {
      yacc = __fmaf_rn(elist[i2], bf2f(vb[(size_t)tlist[i2] * VDN + lane]), yacc);
    }
    y[((size_t)(n * SL + q)) * ODN + h * VDN + lane] = yacc * (0.5f / Z);
  }
}

// ---------------------- y += 0.5*(g @ v)  (single-bf16 MFMA) ----------------
__global__ __launch_bounds__(256) void gv_kernel(float* __restrict__ ws)
{
  const unsigned short* ghi = (const unsigned short*)(ws + G_OFF);
  const int tid = threadIdx.x;
  const int lane = tid & 63;
  const int wave = tid >> 6;
  const int col = lane & 15, grp = lane >> 4;
  const int q0 = blockIdx.x * 64;
  const int hn = blockIdx.y;
  const int h = hn >> 3, n = hn & 7;
  const unsigned short* vthi = (const unsigned short*)(ws + V_OFF) + 4194304u + (size_t)hn * VDN * SL;
  float* y = ws + Y_OFF;

  f32x4 acc[4];
#pragma unroll
  for (int odt = 0; odt < 4; ++odt) acc[odt] = (f32x4){0.f, 0.f, 0.f, 0.f};

  const size_t arow = (size_t)(q0 + wave * 16 + col) * SL;
  for (int ks = 0; ks < 32; ++ks) {
    const bf16x8 ah = *(const bf16x8*)&ghi[arow + ks * 32 + grp * 8];
#pragma unroll
    for (int odt = 0; odt < 4; ++odt) {
      const bf16x8 bh = *(const bf16x8*)&vthi[(size_t)(odt * 16 + col) * SL + ks * 32 + grp * 8];
      acc[odt] = __builtin_amdgcn_mfma_f32_16x16x32_bf16(ah, bh, acc[odt], 0, 0, 0);
    }
  }

#pragma unroll
  for (int odt = 0; odt < 4; ++odt) {
    const int vd = odt * 16 + col;
#pragma unroll
    for (int r = 0; r < 4; ++r) {
      const size_t off = ((size_t)(n * SL + q0 + wave * 16 + grp * 4 + r)) * ODN + h * VDN + vd;
      y[off] += 0.5f * acc[odt][r];
    }
  }
}

// ------------- Wout -> transposed split-bf16 planes (KLO region, post-attn) --
__global__ __launch_bounds__(256) void wtprep_kernel(const float* __restrict__ Wout, float* __restrict__ ws)
{
  __shared__ float tile[64][65];
  unsigned short* wth = (unsigned short*)(ws + KLO_OFF);
  unsigned short* wtl = wth + ODN * ODN;
  const int t = threadIdx.x;
  const int od0 = blockIdx.x * 64;
  const int k0 = blockIdx.y * 64;
  const int r = t >> 2, c4 = (t & 3) * 16;
#pragma unroll
  for (int j = 0; j < 4; ++j) {
    *(float4*)&tile[r][c4 + j * 4] = *(const float4*)&Wout[(size_t)(k0 + r) * ODN + od0 + c4 + j * 4];
  }
  __syncthreads();
  union { unsigned short u[16]; uint4 v[2]; } hi, lo;
#pragma unroll
  for (int j = 0; j < 16; ++j) {
    const float f = tile[c4 + j][r];
    const unsigned short h16 = f2bf(f);
    hi.u[j] = h16;
    lo.u[j] = f2bf(f - bf2f(h16));
  }
  const size_t o = (size_t)(od0 + r) * ODN + k0 + c4;
  *(uint4*)&wth[o] = hi.v[0];
  *(uint4*)&wth[o + 8] = hi.v[1];
  *(uint4*)&wtl[o] = lo.v[0];
  *(uint4*)&wtl[o + 8] = lo.v[1];
}

// ------------------------------------- out = y @ Wout + bout (split MFMA) ---
__global__ __launch_bounds__(256) void out_kernel(
    const float* __restrict__ bout, const float* __restrict__ ws, float* __restrict__ out)
{
  const unsigned short* wth = (const unsigned short*)(ws + KLO_OFF);
  const unsigned short* wtl = wth + ODN * ODN;
  const float* y = ws + Y_OFF;
  const int tid = threadIdx.x;
  const int lane = tid & 63;
  const int wave = tid >> 6;
  const int col = lane & 15, grp = lane >> 4;
  const int od0 = blockIdx.x * 64;
  const int m0 = blockIdx.y * 64 + wave * 16;

  f32x4 acc[4];
#pragma unroll
  for (int odt = 0; odt < 4; ++odt) acc[odt] = (f32x4){0.f, 0.f, 0.f, 0.f};

  const float* yrow = y + (size_t)(m0 + col) * ODN + grp * 8;
  for (int ks = 0; ks < 16; ++ks) {
    const float4 ya = *(const float4*)&yrow[ks * 32];
    const float4 yb = *(const float4*)&yrow[ks * 32 + 4];
    union { unsigned short u[8]; bf16x8 v; } ah, al;
    const float yf[8] = {ya.x, ya.y, ya.z, ya.w, yb.x, yb.y, yb.z, yb.w};
#pragma unroll
    for (int j = 0; j < 8; ++j) {
      const unsigned short h16 = f2bf(yf[j]);
      ah.u[j] = h16;
      al.u[j] = f2bf(yf[j] - bf2f(h16));
    }
#pragma unroll
    for (int odt = 0; odt < 4; ++odt) {
      const size_t bo = (size_t)(od0 + odt * 16 + col) * ODN + ks * 32 + grp * 8;
      const bf16x8 bh = *(const bf16x8*)&wth[bo];
      const bf16x8 bl = *(const bf16x8*)&wtl[bo];
      acc[odt] = __builtin_amdgcn_mfma_f32_16x16x32_bf16(ah.v, bh, acc[odt], 0, 0, 0);
      acc[odt] = __builtin_amdgcn_mfma_f32_16x16x32_bf16(ah.v, bl, acc[odt], 0, 0, 0);
      acc[odt] = __builtin_amdgcn_mfma_f32_16x16x32_bf16(al.v, bh, acc[odt], 0, 0, 0);
    }
  }

#pragma unroll
  for (int odt = 0; odt < 4; ++odt) {
    const int od = od0 + odt * 16 + col;
    const float bo = bout[od];
#pragma unroll
    for (int r = 0; r < 4; ++r) {
      out[(size_t)(m0 + grp * 4 + r) * ODN + od] = acc[odt][r] + bo;
    }
  }
}

extern "C" void kernel_launch(void* const* d_in, const int* in_sizes, int n_in,
                              void* d_out, int out_size, void* d_ws, size_t ws_size,
                              hipStream_t stream)
{
  const float* x     = (const float*)d_in[0];
  const float* Wk    = (const float*)d_in[1];
  const float* bk    = (const float*)d_in[2];
  const float* Wv    = (const float*)d_in[3];
  const float* bv    = (const float*)d_in[4];
  const float* Wout  = (const float*)d_in[5];
  const float* bout  = (const float*)d_in[6];
  const float* graph = (const float*)d_in[7];
  const int*   knn   = (const int*)d_in[8];
  float* out = (float*)d_out;
  float* ws  = (float*)d_ws;

  wprep_kernel<<<dim3(8, 16), 256, 0, stream>>>(Wk, Wv, ws);       // -> G region
  kvproj_kernel<<<dim3(128, 8), 256, 0, stream>>>(x, bk, bv, ws);  // khi/klo + Vbf16 + VT (MFMA)
  gsoftmax_kernel<<<dim3(1024), 256, 0, stream>>>(graph, ws);      // -> g bf16 (G region)
  attn_kernel<<<dim3(64, 64), 512, 0, stream>>>(ws, knn);          // -> y (Y region)
  wtprep_kernel<<<dim3(8, 8), 256, 0, stream>>>(Wout, ws);         // -> Wout' (KLO region)
  gv_kernel<<<dim3(16, 64), 256, 0, stream>>>(ws);                 // y += 0.5*g@v (MFMA)
  out_kernel<<<dim3(8, 128), 256, 0, stream>>>(bout, ws, out);
}

// Round 17
// 485.259 us; speedup vs baseline: 1.0542x; 1.0542x over previous
//
#include <hip/hip_runtime.h>
#include <math.h>

#define NB 8
#define SL 1024
#define DI 512
#define HH 8
#define KDN 64
#define VDN 64
#define ODN 512
#define ATT_SCALE 0.125f

// workspace layout (float units)
// [0,2M)  : KHI bf16 [H*N][S][KD] (8 MB)   (dead after attn)
// KLO_OFF : KLO bf16 (8 MB)                -> after attn: Wout' split planes (1 MB)
// V_OFF   : V bf16 [H*N][S][VD] (8 MB) + VT bf16 [H*N][VD][S] (8 MB)
// G_OFF   : g bf16 [S][S] (2 MB)
// Y_OFF   : y f32 [N][S][H*VD] (16 MB)
#define KLO_OFF 2097152u
#define V_OFF   4194304u
#define G_OFF   8388608u
#define Y_OFF   9437184u

#define ORD_NEG_INF 0x007FFFFFu

typedef __attribute__((ext_vector_type(8))) short bf16x8;
typedef __attribute__((ext_vector_type(4))) float f32x4;

__device__ __forceinline__ unsigned fordu(float f) {
  unsigned b = __float_as_uint(f);
  return b ^ ((b & 0x80000000u) ? 0xFFFFFFFFu : 0x80000000u);
}
__device__ __forceinline__ float ifordu(unsigned k) {
  unsigned b = k ^ ((k & 0x80000000u) ? 0x80000000u : 0xFFFFFFFFu);
  return __uint_as_float(b);
}
__device__ __forceinline__ unsigned short f2bf(float f) {  // RNE f32->bf16
  unsigned u = __float_as_uint(f);
  unsigned r = (u + 0x7FFFu + ((u >> 16) & 1u)) >> 16;
  return (unsigned short)r;
}
__device__ __forceinline__ float bf2f(unsigned short h) {
  return __uint_as_float(((unsigned)h) << 16);
}

// ---------------------------------------------------------------- kv proj ---
// fp32-LDS GEMM (measured-best across r7/r10/r16 MFMA attempts) + fused
// V bf16 + transposed VT bf16 epilogue (r14-verified).
__global__ __launch_bounds__(256) void kvproj_kernel(
    const float* __restrict__ x, const float* __restrict__ Wk, const float* __restrict__ bk,
    const float* __restrict__ Wv, const float* __restrict__ bv, float* __restrict__ ws)
{
  __shared__ float xs[64][68];
  __shared__ float wks[64][68];
  __shared__ float wvs[64][68];
  const int tid = threadIdx.x;
  const int tx = tid & 15, ty = tid >> 4;
  const int m0 = blockIdx.x * 64;
  const int h = blockIdx.y;
  const float* wkb = Wk + (size_t)h * (DI * KDN);
  const float* wvb = Wv + (size_t)h * (DI * VDN);
  float ak[4][4] = {{0.f}};
  float av[4][4] = {{0.f}};
  for (int dt = 0; dt < DI / 64; ++dt) {
    __syncthreads();
#pragma unroll
    for (int it = 0; it < 4; ++it) {
      const int r = ty + it * 16;
      const int c = tx * 4;
      *(float4*)&xs[r][c]  = *(const float4*)&x[(size_t)(m0 + r) * DI + dt * 64 + c];
      *(float4*)&wks[r][c] = *(const float4*)&wkb[(size_t)(dt * 64 + r) * KDN + c];
      *(float4*)&wvs[r][c] = *(const float4*)&wvb[(size_t)(dt * 64 + r) * VDN + c];
    }
    __syncthreads();
#pragma unroll 4
    for (int dd = 0; dd < 64; ++dd) {
      float a[4];
#pragma unroll
      for (int i = 0; i < 4; ++i) a[i] = xs[ty * 4 + i][dd];
      const float4 bkv = *(const float4*)&wks[dd][tx * 4];
      const float4 bvv = *(const float4*)&wvs[dd][tx * 4];
      const float bkj[4] = {bkv.x, bkv.y, bkv.z, bkv.w};
      const float bvj[4] = {bvv.x, bvv.y, bvv.z, bvv.w};
#pragma unroll
      for (int i = 0; i < 4; ++i) {
#pragma unroll
        for (int j = 0; j < 4; ++j) {
          ak[i][j] = __fmaf_rn(a[i], bkj[j], ak[i][j]);
          av[i][j] = __fmaf_rn(a[i], bvj[j], av[i][j]);
        }
      }
    }
  }
  const int n = m0 >> 10;
  const int s0 = m0 & 1023;
  unsigned short* vbf = (unsigned short*)(ws + V_OFF);          // V bf16 [hn][s][vd]
  unsigned short* vtb = vbf + 4194304u;                         // VT bf16 [hn][vd][s]
  unsigned short* khi = (unsigned short*)ws;
  unsigned short* klo = (unsigned short*)(ws + KLO_OFF);
  const size_t hnbase = (size_t)(h * NB + n) * SL;
  __syncthreads();   // done reading xs -> reuse as V transpose tile
#pragma unroll
  for (int i = 0; i < 4; ++i) {
    const int s = s0 + ty * 4 + i;
    union { unsigned short u[4]; uint2 v2; } pv_, ph, pl;
#pragma unroll
    for (int j = 0; j < 4; ++j) {
      const float vf = av[i][j] + bv[h * VDN + tx * 4 + j];
      xs[ty * 4 + i][tx * 4 + j] = vf;
      pv_.u[j] = f2bf(vf);
      const float kf = ak[i][j] + bk[h * KDN + tx * 4 + j];
      const unsigned short h16 = f2bf(kf);
      ph.u[j] = h16;
      pl.u[j] = f2bf(kf - bf2f(h16));
    }
    *(uint2*)&vbf[(hnbase + s) * VDN + tx * 4] = pv_.v2;
    const size_t koff = (hnbase + s) * KDN + tx * 4;
    *(uint2*)&khi[koff] = ph.v2;
    *(uint2*)&klo[koff] = pl.v2;
  }
  __syncthreads();
  // transpose xs[s_local][vd] -> VT[vd][s]
  {
    const int r = tid >> 2, c4 = (tid & 3) * 16;   // r = vd, c4 = s_local chunk
    union { unsigned short u[16]; uint4 v[2]; } hi;
#pragma unroll
    for (int j = 0; j < 16; ++j) hi.u[j] = f2bf(xs[c4 + j][r]);
    unsigned short* vt = vtb + hnbase * VDN;       // == hn * VDN * SL
    const size_t o = (size_t)r * SL + s0 + c4;
    *(uint4*)&vt[o] = hi.v[0];
    *(uint4*)&vt[o + 8] = hi.v[1];
  }
}

// ------------------------------- graph softmax -> bf16 plane (G region) ----
__global__ __launch_bounds__(256) void gsoftmax_kernel(const float* __restrict__ gin, float* __restrict__ ws)
{
  unsigned short* ghi = (unsigned short*)(ws + G_OFF);
  const int row = blockIdx.x;
  const int tid = threadIdx.x;
  const int lane = tid & 63, wave = tid >> 6;
  __shared__ float red[4];
  __shared__ float red2[4];
  float v[4];
  float m = -INFINITY;
#pragma unroll
  for (int i = 0; i < 4; ++i) {
    v[i] = gin[(size_t)row * SL + tid + i * 256];
    m = fmaxf(m, v[i]);
  }
#pragma unroll
  for (int off = 32; off; off >>= 1) m = fmaxf(m, __shfl_xor(m, off));
  if (lane == 0) red[wave] = m;
  __syncthreads();
  m = fmaxf(fmaxf(red[0], red[1]), fmaxf(red[2], red[3]));
  float e[4];
  float s = 0.f;
#pragma unroll
  for (int i = 0; i < 4; ++i) { e[i] = __expf(v[i] - m); s += e[i]; }
#pragma unroll
  for (int off = 32; off; off >>= 1) s += __shfl_xor(s, off);
  if (lane == 0) red2[wave] = s;
  __syncthreads();
  s = red2[0] + red2[1] + red2[2] + red2[3];
  const float inv = 1.0f / s;
#pragma unroll
  for (int i = 0; i < 4; ++i) ghi[(size_t)row * SL + tid + i * 256] = f2bf(e[i] * inv);
}

// -------------------------------------------------------------- attention ---
// Measured-best config (r12/r15): 512 thr / 8 waves / 2 rows per wave,
// bounds (512,8) (mild spill accepted — faster than all no-spill variants),
// bitcast keys + compact-then-exp, bf16-V PV gathers.
__global__ __launch_bounds__(512, 8) void attn_kernel(float* __restrict__ ws, const int* __restrict__ knn_p)
{
  __shared__ float S[16][260];    // 16.6 KB; reused as per-wave lists after capture
  const int tid = threadIdx.x;
  const int lane = tid & 63;
  const int wave = tid >> 6;      // 0..7
  const int q0 = blockIdx.x * 16;
  const int hn = blockIdx.y;
  const int h = hn >> 3, n = hn & 7;
  const int K = knn_p[0];
  const unsigned short* khi = (const unsigned short*)ws + (size_t)hn * SL * KDN;
  const unsigned short* klo = (const unsigned short*)(ws + KLO_OFF) + (size_t)hn * SL * KDN;
  const unsigned short* vb = (const unsigned short*)(ws + V_OFF) + (size_t)hn * (SL * VDN);
  float* y = ws + Y_OFF;

  const int col = lane & 15, grp = lane >> 4;
  const bf16x8 a0h = *(const bf16x8*)&khi[(size_t)(q0 + col) * KDN + grp * 8];
  const bf16x8 a1h = *(const bf16x8*)&khi[(size_t)(q0 + col) * KDN + 32 + grp * 8];
  const bf16x8 a0l = *(const bf16x8*)&klo[(size_t)(q0 + col) * KDN + grp * 8];
  const bf16x8 a1l = *(const bf16x8*)&klo[(size_t)(q0 + col) * KDN + 32 + grp * 8];

  const int T = q0 / 16 + 1;      // causal t-tiles needed
  const int rbase = wave * 2;

  float ev[2][8][2];              // per-row KEYS (never overwritten), static-indexed
#pragma unroll
  for (int rr = 0; rr < 2; ++rr)
#pragma unroll
    for (int c = 0; c < 8; ++c) {
      ev[rr][c][0] = __uint_as_float(ORD_NEG_INF);
      ev[rr][c][1] = __uint_as_float(ORD_NEG_INF);
    }

#pragma unroll
  for (int ph = 0; ph < 4; ++ph) {
    const int tlo = ph * 16;
    const int thi = (T < tlo + 16) ? T : (tlo + 16);
    if (thi > tlo) {            // block-uniform
      __syncthreads();
      for (int ti = tlo + wave; ti < thi; ti += 8) {
        const int t0 = ti * 16;
        const size_t bo = (size_t)(t0 + col) * KDN + grp * 8;
        const bf16x8 b0h = *(const bf16x8*)&khi[bo];
        const bf16x8 b1h = *(const bf16x8*)&khi[bo + 32];
        const bf16x8 b0l = *(const bf16x8*)&klo[bo];
        const bf16x8 b1l = *(const bf16x8*)&klo[bo + 32];
        f32x4 d = {0.f, 0.f, 0.f, 0.f};
        d = __builtin_amdgcn_mfma_f32_16x16x32_bf16(a0h, b0h, d, 0, 0, 0);
        d = __builtin_amdgcn_mfma_f32_16x16x32_bf16(a1h, b1h, d, 0, 0, 0);
        d = __builtin_amdgcn_mfma_f32_16x16x32_bf16(a0h, b0l, d, 0, 0, 0);
        d = __builtin_amdgcn_mfma_f32_16x16x32_bf16(a1h, b1l, d, 0, 0, 0);
        d = __builtin_amdgcn_mfma_f32_16x16x32_bf16(a0l, b0h, d, 0, 0, 0);
        d = __builtin_amdgcn_mfma_f32_16x16x32_bf16(a1l, b1h, d, 0, 0, 0);
        d = __builtin_amdgcn_mfma_f32_16x16x32_bf16(a0l, b0l, d, 0, 0, 0);
        d = __builtin_amdgcn_mfma_f32_16x16x32_bf16(a1l, b1l, d, 0, 0, 0);
        const int tl = t0 - ph * 256 + col;
#pragma unroll
        for (int r = 0; r < 4; ++r) S[grp * 4 + r][tl] = d[r];
      }
      __syncthreads();
#pragma unroll
      for (int rr = 0; rr < 2; ++rr) {
        const int q = q0 + rbase + rr;
        const int cmr = q >> 7;
#pragma unroll
        for (int cc = 0; cc < 2; ++cc) {
          const int c = ph * 2 + cc;
          if (c <= cmr) {
            const float2 sv = *(const float2*)&S[rbase + rr][cc * 128 + lane * 2];
            const int t0 = c * 128 + lane * 2;
            const unsigned k0 = (t0     <= q) ? fordu(sv.x * ATT_SCALE) : ORD_NEG_INF;
            const unsigned k1 = (t0 + 1 <= q) ? fordu(sv.y * ATT_SCALE) : ORD_NEG_INF;
            ev[rr][c][0] = __uint_as_float(k0);
            ev[rr][c][1] = __uint_as_float(k1);
          }
        }
      }
    }
  }
  __syncthreads();  // all rows captured -> reuse S as per-wave scratch

  float* elist = (float*)((char*)&S[0][0] + wave * 768);   // 128 f32 (8 waves x 768B = 6 KB)
  unsigned short* tlist = (unsigned short*)(elist + 128);  // 128 u16

#pragma unroll
  for (int rr = 0; rr < 2; ++rr) {
    const int q = q0 + rbase + rr;

    // ---- lane-max, wave max (mk), wave min-of-lane-maxes (t0k) on key bits ----
    unsigned lmax = __float_as_uint(ev[rr][0][0]);
#pragma unroll
    for (int c = 0; c < 8; ++c) {
      const unsigned a = __float_as_uint(ev[rr][c][0]);
      const unsigned b = __float_as_uint(ev[rr][c][1]);
      lmax = lmax > a ? lmax : a;
      lmax = lmax > b ? lmax : b;
    }
    unsigned mk = lmax, t0k = lmax;
#pragma unroll
    for (int off = 32; off; off >>= 1) {
      const unsigned om = (unsigned)__shfl_xor((int)mk, off);
      const unsigned ot = (unsigned)__shfl_xor((int)t0k, off);
      mk = mk > om ? mk : om;
      t0k = t0k < ot ? t0k : ot;
    }
    const float m = ifordu(mk);

    // ---- exact Kth-largest key: binary search on rank ----
    unsigned kth;
    if (q < K) {
      kth = ORD_NEG_INF;
    } else {
      unsigned lo = (K <= 64) ? t0k : 0u;
      unsigned hi = mk;
      while (lo < hi) {
        const unsigned mid = lo + ((hi - lo + 1) >> 1);
        int cnt = 0;
#pragma unroll
        for (int c = 0; c < 8; ++c) {
          cnt += (int)__popcll(__ballot(__float_as_uint(ev[rr][c][0]) >= mid));
          cnt += (int)__popcll(__ballot(__float_as_uint(ev[rr][c][1]) >= mid));
        }
        if (cnt >= K) lo = mid; else hi = mid - 1;
      }
      kth = lo;
    }

    // ---- compact kept KEYS into per-wave LDS lists (cap 128) ----
    const unsigned long long lt = (1ull << lane) - 1ull;
    int cnt = 0;
#pragma unroll
    for (int c = 0; c < 8; ++c) {
#pragma unroll
      for (int j = 0; j < 2; ++j) {
        const unsigned k = __float_as_uint(ev[rr][c][j]);
        const bool keep = (k >= kth) && (k != ORD_NEG_INF);
        const unsigned long long msk = __ballot(keep);
        if (keep) {
          const int pos = cnt + (int)__popcll(msk & lt);
          if (pos < 128) {
            elist[pos] = ev[rr][c][j];   // store KEY bits
            tlist[pos] = (unsigned short)(c * 128 + lane * 2 + j);
          }
        }
        cnt += (int)__popcll(msk);
      }
    }
    cnt = (cnt < 128) ? cnt : 128;

    // ---- exp only compacted entries (<=2/lane); Z via wave reduce ----
    float zp = 0.f;
    if (lane < cnt) {
      const float e = __expf(ifordu(__float_as_uint(elist[lane])) - m);
      elist[lane] = e;
      zp += e;
    }
    if (lane + 64 < cnt) {
      const float e = __expf(ifordu(__float_as_uint(elist[lane + 64])) - m);
      elist[lane + 64] = e;
      zp += e;
    }
    float Z = zp;
#pragma unroll
    for (int off = 32; off; off >>= 1) Z += __shfl_xor(Z, off);

    // ---- sparse PV: lane = vd (V gathered as bf16) ----
    float yacc = 0.f;
    int i2 = 0;
    for (; i2 + 4 <= cnt; i2 += 4) {
      const float4 e4 = *(const float4*)&elist[i2];
      const ushort4 t4 = *(const ushort4*)&tlist[i2];
      const float v0 = bf2f(vb[(size_t)t4.x * VDN + lane]);
      const float v1 = bf2f(vb[(size_t)t4.y * VDN + lane]);
      const float v2 = bf2f(vb[(size_t)t4.z * VDN + lane]);
      const float v3 = bf2f(vb[(size_t)t4.w * VDN + lane]);
      yacc = __fmaf_rn(e4.x, v0, yacc);
      yacc = __fmaf_rn(e4.y, v1, yacc);
      yacc = __fmaf_rn(e4.z, v2, yacc);
      yacc = __fmaf_rn(e4.w, v3, yacc);
    }
    for (; i2 < cnt; ++i2) {
      yacc = __fmaf_rn(elist[i2], bf2f(vb[(size_t)tlist[i2] * VDN + lane]), yacc);
    }
    y[((size_t)(n * SL + q)) * ODN + h * VDN + lane] = yacc * (0.5f / Z);
  }
}

// ---------------------- y += 0.5*(g @ v)  (single-bf16 MFMA) ----------------
__global__ __launch_bounds__(256) void gv_kernel(float* __restrict__ ws)
{
  const unsigned short* ghi = (const unsigned short*)(ws + G_OFF);
  const int tid = threadIdx.x;
  const int lane = tid & 63;
  const int wave = tid >> 6;
  const int col = lane & 15, grp = lane >> 4;
  const int q0 = blockIdx.x * 64;
  const int hn = blockIdx.y;
  const int h = hn >> 3, n = hn & 7;
  const unsigned short* vthi = (const unsigned short*)(ws + V_OFF) + 4194304u + (size_t)hn * VDN * SL;
  float* y = ws + Y_OFF;

  f32x4 acc[4];
#pragma unroll
  for (int odt = 0; odt < 4; ++odt) acc[odt] = (f32x4){0.f, 0.f, 0.f, 0.f};

  const size_t arow = (size_t)(q0 + wave * 16 + col) * SL;
  for (int ks = 0; ks < 32; ++ks) {
    const bf16x8 ah = *(const bf16x8*)&ghi[arow + ks * 32 + grp * 8];
#pragma unroll
    for (int odt = 0; odt < 4; ++odt) {
      const bf16x8 bh = *(const bf16x8*)&vthi[(size_t)(odt * 16 + col) * SL + ks * 32 + grp * 8];
      acc[odt] = __builtin_amdgcn_mfma_f32_16x16x32_bf16(ah, bh, acc[odt], 0, 0, 0);
    }
  }

#pragma unroll
  for (int odt = 0; odt < 4; ++odt) {
    const int vd = odt * 16 + col;
#pragma unroll
    for (int r = 0; r < 4; ++r) {
      const size_t off = ((size_t)(n * SL + q0 + wave * 16 + grp * 4 + r)) * ODN + h * VDN + vd;
      y[off] += 0.5f * acc[odt][r];
    }
  }
}

// ------------- Wout -> transposed split-bf16 planes (KLO region, post-attn) --
__global__ __launch_bounds__(256) void wtprep_kernel(const float* __restrict__ Wout, float* __restrict__ ws)
{
  __shared__ float tile[64][65];
  unsigned short* wth = (unsigned short*)(ws + KLO_OFF);
  unsigned short* wtl = wth + ODN * ODN;
  const int t = threadIdx.x;
  const int od0 = blockIdx.x * 64;
  const int k0 = blockIdx.y * 64;
  const int r = t >> 2, c4 = (t & 3) * 16;
#pragma unroll
  for (int j = 0; j < 4; ++j) {
    *(float4*)&tile[r][c4 + j * 4] = *(const float4*)&Wout[(size_t)(k0 + r) * ODN + od0 + c4 + j * 4];
  }
  __syncthreads();
  union { unsigned short u[16]; uint4 v[2]; } hi, lo;
#pragma unroll
  for (int j = 0; j < 16; ++j) {
    const float f = tile[c4 + j][r];
    const unsigned short h16 = f2bf(f);
    hi.u[j] = h16;
    lo.u[j] = f2bf(f - bf2f(h16));
  }
  const size_t o = (size_t)(od0 + r) * ODN + k0 + c4;
  *(uint4*)&wth[o] = hi.v[0];
  *(uint4*)&wth[o + 8] = hi.v[1];
  *(uint4*)&wtl[o] = lo.v[0];
  *(uint4*)&wtl[o + 8] = lo.v[1];
}

// ------------------------------------- out = y @ Wout + bout (split MFMA) ---
__global__ __launch_bounds__(256) void out_kernel(
    const float* __restrict__ bout, const float* __restrict__ ws, float* __restrict__ out)
{
  const unsigned short* wth = (const unsigned short*)(ws + KLO_OFF);
  const unsigned short* wtl = wth + ODN * ODN;
  const float* y = ws + Y_OFF;
  const int tid = threadIdx.x;
  const int lane = tid & 63;
  const int wave = tid >> 6;
  const int col = lane & 15, grp = lane >> 4;
  const int od0 = blockIdx.x * 64;
  const int m0 = blockIdx.y * 64 + wave * 16;

  f32x4 acc[4];
#pragma unroll
  for (int odt = 0; odt < 4; ++odt) acc[odt] = (f32x4){0.f, 0.f, 0.f, 0.f};

  const float* yrow = y + (size_t)(m0 + col) * ODN + grp * 8;
  for (int ks = 0; ks < 16; ++ks) {
    const float4 ya = *(const float4*)&yrow[ks * 32];
    const float4 yb = *(const float4*)&yrow[ks * 32 + 4];
    union { unsigned short u[8]; bf16x8 v; } ah, al;
    const float yf[8] = {ya.x, ya.y, ya.z, ya.w, yb.x, yb.y, yb.z, yb.w};
#pragma unroll
    for (int j = 0; j < 8; ++j) {
      const unsigned short h16 = f2bf(yf[j]);
      ah.u[j] = h16;
      al.u[j] = f2bf(yf[j] - bf2f(h16));
    }
#pragma unroll
    for (int odt = 0; odt < 4; ++odt) {
      const size_t bo = (size_t)(od0 + odt * 16 + col) * ODN + ks * 32 + grp * 8;
      const bf16x8 bh = *(const bf16x8*)&wth[bo];
      const bf16x8 bl = *(const bf16x8*)&wtl[bo];
      acc[odt] = __builtin_amdgcn_mfma_f32_16x16x32_bf16(ah.v, bh, acc[odt], 0, 0, 0);
      acc[odt] = __builtin_amdgcn_mfma_f32_16x16x32_bf16(ah.v, bl, acc[odt], 0, 0, 0);
      acc[odt] = __builtin_amdgcn_mfma_f32_16x16x32_bf16(al.v, bh, acc[odt], 0, 0, 0);
    }
  }

#pragma unroll
  for (int odt = 0; odt < 4; ++odt) {
    const int od = od0 + odt * 16 + col;
    const float bo = bout[od];
#pragma unroll
    for (int r = 0; r < 4; ++r) {
      out[(size_t)(m0 + grp * 4 + r) * ODN + od] = acc[odt][r] + bo;
    }
  }
}

extern "C" void kernel_launch(void* const* d_in, const int* in_sizes, int n_in,
                              void* d_out, int out_size, void* d_ws, size_t ws_size,
                              hipStream_t stream)
{
  const float* x     = (const float*)d_in[0];
  const float* Wk    = (const float*)d_in[1];
  const float* bk    = (const float*)d_in[2];
  const float* Wv    = (const float*)d_in[3];
  const float* bv    = (const float*)d_in[4];
  const float* Wout  = (const float*)d_in[5];
  const float* bout  = (const float*)d_in[6];
  const float* graph = (const float*)d_in[7];
  const int*   knn   = (const int*)d_in[8];
  float* out = (float*)d_out;
  float* ws  = (float*)d_ws;

  kvproj_kernel<<<dim3(128, 8), 256, 0, stream>>>(x, Wk, bk, Wv, bv, ws);  // khi/klo + Vbf16 + VT
  gsoftmax_kernel<<<dim3(1024), 256, 0, stream>>>(graph, ws);     // -> g bf16 (G region)
  attn_kernel<<<dim3(64, 64), 512, 0, stream>>>(ws, knn);         // -> y (Y region)
  wtprep_kernel<<<dim3(8, 8), 256, 0, stream>>>(Wout, ws);        // -> Wout' (KLO region)
  gv_kernel<<<dim3(16, 64), 256, 0, stream>>>(ws);                // y += 0.5*g@v (MFMA)
  out_kernel<<<dim3(8, 128), 256, 0, stream>>>(bout, ws, out);
}